// Round 5
// baseline (191.375 us; speedup 1.0000x reference)
//
#include <hip/hip_runtime.h>

typedef _Float16 f16;
typedef _Float16 f16x4 __attribute__((ext_vector_type(4)));
typedef _Float16 f16x8 __attribute__((ext_vector_type(8)));
typedef float f32x4 __attribute__((ext_vector_type(4)));

// ws layout
#define WS_QKW   0                       // [8b][8e][256c] f16 = 32 KiB
#define WS_MTP   32768                   // [256kc][256o][8] f16 = 1 MiB
#define WS_FLAGS (32768 + 1048576)       // 2 int counters (+pad 128)
#define WS_X1    (WS_FLAGS + 128)        // [8b][512] f32 = 16 KiB
#define WS_QH    (WS_X1 + 16384)         // [8b][512] f32 = 16 KiB

// A[px][k]: 32 px rows x 2048 f16 (4096 B per row). 16-B chunks XOR-swizzled
// by px (4 bits): byte = px*4096 + ((k>>3)^(px&15))*16 + (k&7)*2.
static __device__ inline char* a_addr(char* Abase, int px, int k) {
    return Abase + px * 4096 + ((((k >> 3) ^ (px & 15)) << 4) | ((k & 7) << 1));
}

// device-scope producer/consumer sync (all blocks co-resident: grid 160 < 256 CUs)
static __device__ inline void post_count(int* f) {
    __threadfence();                      // every thread publishes its stores
    __syncthreads();                      // all fences complete
    if (threadIdx.x == 0)
        __hip_atomic_fetch_add(f, 1, __ATOMIC_RELEASE, __HIP_MEMORY_SCOPE_AGENT);
}
static __device__ inline void wait_count(int* f, int target) {
    if (threadIdx.x == 0) {
        while (__hip_atomic_load(f, __ATOMIC_ACQUIRE, __HIP_MEMORY_SCOPE_AGENT) < target)
            __builtin_amdgcn_s_sleep(8);
    }
    __syncthreads();
}

// ---------------------------------------------------------------------------
// k_setup v5: grid 160 x 1024, ONE launch, stage-parallel query path.
// blocks 0..31:   stage1  x1[8][16-h slice]  (w1 16 KB/block)
// blocks 32..63:  stage2  qh[8][16-o slice]  (w2 32 KB/block)   waits f0==32
// blocks 64..95:  stage3  qkw[8][8][8-c slice] (w_kv 16 KB/blk) waits f1==32
// blocks 96..159: M role (R4 verbatim): M_e = Wv_e @ w_out_e -> mtp
// ---------------------------------------------------------------------------
__launch_bounds__(1024)
__global__ void k_setup(const int* __restrict__ q, const float* __restrict__ emb,
                        const float* __restrict__ w1, const float* __restrict__ b1,
                        const float* __restrict__ w2, const float* __restrict__ b2,
                        const float* __restrict__ w_kv, const float* __restrict__ w_out,
                        const float* __restrict__ rms_w,
                        f16* __restrict__ qkw, f16* __restrict__ mtp,
                        float* __restrict__ x1g, float* __restrict__ qhg,
                        int* __restrict__ flags) {
    int blk = blockIdx.x;
    int t = threadIdx.x;

    if (blk < 32) {
        // ---- stage1: x1 = silu(qe @ w1 + b1), 16-h slice ----
        __shared__ float qe[8][256];      // 8 KB
        __shared__ float ps[8][8][16];    // 4 KB
        int hs = blk * 16;
        for (int i = t; i < 2048; i += 1024) {
            int bb = i >> 8, c = i & 255;
            qe[bb][c] = emb[(size_t)q[bb] * 256 + c];
        }
        __syncthreads();
        {
            int hl = t & 15, b = (t >> 4) & 7, qq = t >> 7;   // qq 0..7
            int h = hs + hl;
            float acc = 0.f;
#pragma unroll
            for (int c = qq * 32; c < qq * 32 + 32; ++c)
                acc += qe[b][c] * w1[(size_t)c * 512 + h];
            ps[qq][b][hl] = acc;
        }
        __syncthreads();
        if (t < 128) {
            int b = t >> 4, hl = t & 15;
            float a = b1[hs + hl];
#pragma unroll
            for (int qq = 0; qq < 8; ++qq) a += ps[qq][b][hl];
            x1g[b * 512 + hs + hl] = a / (1.f + __expf(-a));
        }
        post_count(&flags[0]);
    } else if (blk < 64) {
        // ---- stage2: qh = x1 @ w2 + b2, 16-o slice ----
        __shared__ float x1L[8][512];     // 16 KB
        __shared__ float ps[8][8][16];    // 4 KB
        int os = (blk - 32) * 16;
        wait_count(&flags[0], 32);
        for (int i = t; i < 4096; i += 1024) {
            int bb = i >> 9, k = i & 511;
            x1L[bb][k] = x1g[bb * 512 + k];
        }
        __syncthreads();
        {
            int ol = t & 15, b = (t >> 4) & 7, qq = t >> 7;   // qq 0..7, 64 k each
            int o = os + ol;
            float acc = 0.f;
#pragma unroll 16
            for (int k = qq * 64; k < qq * 64 + 64; ++k)
                acc += x1L[b][k] * w2[(size_t)k * 512 + o];
            ps[qq][b][ol] = acc;
        }
        __syncthreads();
        if (t < 128) {
            int b = t >> 4, ol = t & 15;
            float a = b2[os + ol];
#pragma unroll
            for (int qq = 0; qq < 8; ++qq) a += ps[qq][b][ol];
            qhg[b * 512 + os + ol] = a;
        }
        post_count(&flags[1]);
    } else if (blk < 96) {
        // ---- stage3: qkw[b,e,c] = rms_w[c] * <qh[b,e*64..], wkvK[c,e]>, 8-c slice ----
        __shared__ float qhL[8][512];     // 16 KB
        __shared__ float ps2[512];        //  2 KB
        int cs = (blk - 64) * 8;
        wait_count(&flags[1], 32);
        for (int i = t; i < 4096; i += 1024) {
            int bb = i >> 9, k = i & 511;
            qhL[bb][k] = qhg[bb * 512 + k];
        }
        __syncthreads();
        int cl = t & 7, e = (t >> 3) & 7, b = (t >> 6) & 7, dh = t >> 9;
        int c = cs + cl;
        const float* col = w_kv + (size_t)c * 1024 + e * 128 + dh * 32;  // K-half
        float acc = 0.f;
#pragma unroll
        for (int dq = 0; dq < 8; ++dq) {
            float4 wv4 = *(const float4*)(col + dq * 4);
            const float* qb = &qhL[b][e * 64 + dh * 32 + dq * 4];
            acc += wv4.x * qb[0] + wv4.y * qb[1] + wv4.z * qb[2] + wv4.w * qb[3];
        }
        if (dh) ps2[t - 512] = acc;
        __syncthreads();
        if (t < 512)
            qkw[((size_t)b * 8 + e) * 256 + c] = (f16)((acc + ps2[t]) * rms_w[c]);
    } else {
        // ---- M role: 4 subtiles of (e, 8-c tile); inner loop = R0 verbatim ----
        __shared__ float wv[4][64][8];
        int sub = t >> 8, st = t & 255;
        int mb = (blk - 96) * 4 + sub;
        int e = mb >> 5, c0 = (mb & 31) * 8;
        {
            int d = st & 63, cc = st >> 6;
            wv[sub][d][cc]     = w_kv[(size_t)(c0 + cc) * 1024 + e * 128 + 64 + d];
            wv[sub][d][cc + 4] = w_kv[(size_t)(c0 + cc + 4) * 1024 + e * 128 + 64 + d];
        }
        __syncthreads();
        int o = st;
        float acc[8];
#pragma unroll
        for (int c = 0; c < 8; ++c) acc[c] = 0.f;
#pragma unroll 4
        for (int d = 0; d < 64; ++d) {
            float wo = w_out[(size_t)(e * 64 + d) * 256 + o];
            float4 wa = *(const float4*)&wv[sub][d][0];
            float4 wb = *(const float4*)&wv[sub][d][4];
            acc[0] += wa.x * wo; acc[1] += wa.y * wo; acc[2] += wa.z * wo; acc[3] += wa.w * wo;
            acc[4] += wb.x * wo; acc[5] += wb.y * wo; acc[6] += wb.z * wo; acc[7] += wb.w * wo;
        }
        f16x8 ov;
#pragma unroll
        for (int c = 0; c < 8; ++c) ov[c] = (f16)(acc[c] * rms_w[c0 + c]);
        *(f16x8*)(mtp + ((size_t)((e * 256 + c0) >> 3) * 256 + o) * 8) = ov;
    }
}

// ---------------------------------------------------------------------------
// k_attn v4 (UNCHANGED from R4, measured 44.1 us): 32-px tiles, one-shot
// attn-compute, cheap blend, fused GEMM.
// ---------------------------------------------------------------------------
__launch_bounds__(1024, 4)
__global__ void k_attn(const float* __restrict__ cin, const f16* __restrict__ qkw,
                       const f16* __restrict__ mtp, const float* __restrict__ b_out,
                       float* __restrict__ out) {
    int blk = blockIdx.x;
    int b = blk & 7;
    int hw0 = (blk >> 3) * 32;
    int t = threadIdx.x;
    int lane = t & 63, w = t >> 6;        // w 0..15
    int m16 = lane & 15, quad = lane >> 4;
    int half = lane >> 5;                 // 0/1

    __shared__ char A[32 * 4096];         // 131072 B, swizzled f16 [32px][2048k]
    __shared__ float dotsP[8][8][32];     //   8192 B [n][e][px]
    __shared__ char pool[16384];          // wred f32[16][8][32] -> attn f16[8][32][8]
    __shared__ float rinvL[32][8];        //   1024 B

    float* wredF = (float*)pool;          // wredF[w*256 + g*32 + px]
    f16*   attnH = (f16*)pool;            // attnH[e*256 + px*8 + n]

    // ---- load raw c -> A (f16, swizzled): thread = (px, 8-ch block cb) ----
    int px = lane & 31;
    int cb = w + half * 16;               // halves 16 apart -> 2-way stores
    const float* cbase = cin + ((size_t)b * 8 * 256) * 1024 + hw0 + px;
#pragma unroll
    for (int g = 0; g < 8; g += 2) {      // g-pair: 16 loads in flight
        const float* s0 = cbase + ((size_t)(g * 256 + cb * 8) << 10);
        const float* s1 = cbase + ((size_t)((g + 1) * 256 + cb * 8) << 10);
        float v0[8], v1[8];
#pragma unroll
        for (int j = 0; j < 8; ++j) v0[j] = s0[(size_t)j << 10];
#pragma unroll
        for (int j = 0; j < 8; ++j) v1[j] = s1[(size_t)j << 10];
        float sa = 0.f, sb = 0.f;
        f16x8 h0, h1;
#pragma unroll
        for (int j = 0; j < 8; ++j) { sa += v0[j] * v0[j]; h0[j] = (f16)v0[j]; }
#pragma unroll
        for (int j = 0; j < 8; ++j) { sb += v1[j] * v1[j]; h1[j] = (f16)v1[j]; }
        *(f16x8*)a_addr(A, px, g * 256 + cb * 8)       = h0;
        *(f16x8*)a_addr(A, px, (g + 1) * 256 + cb * 8) = h1;
        sa += __shfl_xor(sa, 32);         // combine the two cb halves (same px)
        sb += __shfl_xor(sb, 32);
        if (lane < 32) {
            wredF[w * 256 + g * 32 + px]       = sa;
            wredF[w * 256 + (g + 1) * 32 + px] = sb;
        }
    }
    __syncthreads();

    // ---- rinv (t<256) + dots via MFMA (wave w -> n=w&7, px-half=w>>3) ----
    if (t < 256) {
        int p = t >> 3, n = t & 7;
        float ss = 0.f;
#pragma unroll
        for (int ww = 0; ww < 16; ++ww) ss += wredF[ww * 256 + n * 32 + p];
        rinvL[p][n] = rsqrtf(ss * (1.f / 256.f) + 1e-6f);
    }
    {
        int n = w & 7, pxh = w >> 3;
        f32x4 d0 = {0.f, 0.f, 0.f, 0.f};
        const f16* qrow = qkw + (size_t)b * 2048 + (m16 & 7) * 256;
#pragma unroll
        for (int ks = 0; ks < 8; ++ks) {
            f16x8 a0  = *(const f16x8*)a_addr(A, pxh * 16 + m16, n * 256 + ks * 32 + quad * 8);
            f16x8 bfr = *(const f16x8*)(qrow + ks * 32 + quad * 8);
            d0 = __builtin_amdgcn_mfma_f32_16x16x32_f16(a0, bfr, d0, 0, 0, 0);
        }
        if (m16 < 8) {   // D: col=m16=e, row=quad*4+r
#pragma unroll
            for (int r = 0; r < 4; ++r) dotsP[n][m16][pxh * 16 + quad * 4 + r] = d0[r];
        }
    }
    __syncthreads();

    // ---- GEMM B-frag preload (ks 0..7), in flight across attn+blend ----
    int o = w * 16 + m16;
    f16x8 pb[8];
#pragma unroll
    for (int ks = 0; ks < 8; ++ks)
        pb[ks] = *(const f16x8*)(mtp + ((size_t)(ks * 4 + quad) * 256 + o) * 8);

    // ---- attn-compute: one softmax per (px,e), packed f16x8 over n ----
    if (t < 256) {
        int e = t >> 5, p = t & 31;       // lanes p-consecutive
        float rv[8], l[8];
#pragma unroll
        for (int n = 0; n < 8; ++n) rv[n] = rinvL[p][n];
#pragma unroll
        for (int n = 0; n < 8; ++n) l[n] = dotsP[n][e][p] * rv[n] * 0.125f;
        float mx = l[0];
#pragma unroll
        for (int n = 1; n < 8; ++n) mx = fmaxf(mx, l[n]);
        float s = 0.f;
#pragma unroll
        for (int n = 0; n < 8; ++n) { l[n] = __expf(l[n] - mx); s += l[n]; }
        float inv = 1.f / s;
        f16x8 av;
#pragma unroll
        for (int n = 0; n < 8; ++n) av[n] = (f16)(l[n] * inv * rv[n]);
        *(f16x8*)(attnH + e * 256 + p * 8) = av;
    }
    __syncthreads();

    // ---- cheap blend (in place over A): no per-window softmax ----
    {
        int bpx = lane & 31;
        int c0 = (w + half * 16) * 8;     // halves 16 windows apart -> 2-way
        f16x8 cv[8];
#pragma unroll
        for (int n = 0; n < 8; ++n)
            cv[n] = *(const f16x8*)a_addr(A, bpx, n * 256 + c0);
#pragma unroll
        for (int e = 0; e < 8; ++e) {
            f16x8 av = *(const f16x8*)(attnH + e * 256 + bpx * 8);
            f16x8 r = {};
#pragma unroll
            for (int n = 0; n < 8; ++n) {
                f16 an = av[n];
#pragma unroll
                for (int j = 0; j < 8; ++j) r[j] += cv[n][j] * an;   // v_pk_fma_f16
            }
            *(f16x8*)a_addr(A, bpx, e * 256 + c0) = r;
        }
    }
    __syncthreads();

    // ---- GEMM: out[32p][256o] = A[32][2048] @ M  (wave w -> o 16-slice) ----
    {
        f32x4 acc0 = {0.f, 0.f, 0.f, 0.f};
        f32x4 acc1 = {0.f, 0.f, 0.f, 0.f};
#pragma unroll
        for (int ks = 0; ks < 8; ++ks) {   // preloaded B
            int k = ks * 32 + quad * 8;
            f16x8 af0 = *(const f16x8*)a_addr(A, m16, k);
            f16x8 af1 = *(const f16x8*)a_addr(A, m16 + 16, k);
            acc0 = __builtin_amdgcn_mfma_f32_16x16x32_f16(af0, pb[ks], acc0, 0, 0, 0);
            acc1 = __builtin_amdgcn_mfma_f32_16x16x32_f16(af1, pb[ks], acc1, 0, 0, 0);
        }
#pragma unroll 8
        for (int ks = 8; ks < 64; ++ks) {
            int k = (ks >> 3) * 256 + (ks & 7) * 32 + quad * 8;
            int kchunk = k >> 3;
            f16x8 bfr = *(const f16x8*)(mtp + ((size_t)kchunk * 256 + o) * 8);
            f16x8 af0 = *(const f16x8*)a_addr(A, m16, k);
            f16x8 af1 = *(const f16x8*)a_addr(A, m16 + 16, k);
            acc0 = __builtin_amdgcn_mfma_f32_16x16x32_f16(af0, bfr, acc0, 0, 0, 0);
            acc1 = __builtin_amdgcn_mfma_f32_16x16x32_f16(af1, bfr, acc1, 0, 0, 0);
        }
        float bo = b_out[o];
        float* drow = out + ((size_t)b * 256 + o) * 1024 + hw0;
        float4 v0 = {acc0[0] + bo, acc0[1] + bo, acc0[2] + bo, acc0[3] + bo};
        float4 v1 = {acc1[0] + bo, acc1[1] + bo, acc1[2] + bo, acc1[3] + bo};
        *(float4*)(drow + quad * 4)      = v0;   // px 0..15 half
        *(float4*)(drow + 16 + quad * 4) = v1;   // px 16..31 half
    }
}

extern "C" void kernel_launch(void* const* d_in, const int* in_sizes, int n_in,
                              void* d_out, int out_size, void* d_ws, size_t ws_size,
                              hipStream_t stream) {
    (void)in_sizes; (void)n_in; (void)out_size; (void)ws_size;
    const int*   q     = (const int*)d_in[0];
    const float* c     = (const float*)d_in[1];
    const float* rms_w = (const float*)d_in[2];
    const float* emb   = (const float*)d_in[3];
    const float* w1    = (const float*)d_in[4];
    const float* b1    = (const float*)d_in[5];
    const float* w2    = (const float*)d_in[6];
    const float* b2    = (const float*)d_in[7];
    const float* w_kv  = (const float*)d_in[8];
    const float* w_out = (const float*)d_in[9];
    const float* b_out = (const float*)d_in[10];
    float* out = (float*)d_out;

    char* ws = (char*)d_ws;
    f16*   qkw   = (f16*)(ws + WS_QKW);
    f16*   mtp   = (f16*)(ws + WS_MTP);
    int*   flags = (int*)(ws + WS_FLAGS);
    float* x1g   = (float*)(ws + WS_X1);
    float* qhg   = (float*)(ws + WS_QH);

    hipMemsetAsync(flags, 0, 64, stream);   // reset stage counters each iteration
    k_setup<<<160, 1024, 0, stream>>>(q, emb, w1, b1, w2, b2, w_kv, w_out, rms_w,
                                      qkw, mtp, x1g, qhg, flags);
    k_attn <<<256, 1024, 0, stream>>>(c, qkw, mtp, b_out, out);
}

// Round 7
// 168.035 us; speedup vs baseline: 1.1389x; 1.1389x over previous
//
#include <hip/hip_runtime.h>

typedef _Float16 f16;
typedef _Float16 f16x4 __attribute__((ext_vector_type(4)));
typedef _Float16 f16x8 __attribute__((ext_vector_type(8)));
typedef float f32x4 __attribute__((ext_vector_type(4)));

// A[px][k]: 32 px rows x 2048 f16 (4096 B per row). 16-B chunks XOR-swizzled
// by px (4 bits): byte = px*4096 + ((k>>3)^(px&15))*16 + (k&7)*2.
static __device__ inline char* a_addr(char* Abase, int px, int k) {
    return Abase + px * 4096 + ((((k >> 3) ^ (px & 15)) << 4) | ((k & 7) << 1));
}

// ---------------------------------------------------------------------------
// k_setup (R0 verbatim — harness-proven): one launch, no internal deps.
// blocks 0..63:   (b,e): full query path redundantly
// blocks 64..319: M_e = Wv_e @ w_out_e, rw-folded -> mtp[kchunk][o][8] f16
// ---------------------------------------------------------------------------
__launch_bounds__(256)
__global__ void k_setup(const int* __restrict__ q, const float* __restrict__ emb,
                        const float* __restrict__ w1, const float* __restrict__ b1,
                        const float* __restrict__ w2, const float* __restrict__ b2,
                        const float* __restrict__ w_kv, const float* __restrict__ w_out,
                        const float* __restrict__ rms_w,
                        f16* __restrict__ qkw, f16* __restrict__ mtp) {
    int blk = blockIdx.x;
    int t = threadIdx.x;
    __shared__ float qe[256];
    __shared__ float x1L[512];
    __shared__ float ps[4][64];
    __shared__ float qhL[64];
    __shared__ float wv[64][8];

    if (blk < 64) {
        // ---- query-path role: (b, e) ----
        int b = blk >> 3, e = blk & 7;
        qe[t] = emb[(size_t)q[b] * 256 + t];
        __syncthreads();
        float a0 = b1[t], a1 = b1[t + 256];
#pragma unroll 4
        for (int c = 0; c < 256; ++c) {
            float qv = qe[c];
            a0 += qv * w1[c * 512 + t];
            a1 += qv * w1[c * 512 + t + 256];
        }
        x1L[t]       = a0 / (1.f + __expf(-a0));
        x1L[t + 256] = a1 / (1.f + __expf(-a1));
        __syncthreads();
        int d = t & 63, ks = t >> 6;
        float acc = 0.f;
#pragma unroll 4
        for (int k = ks * 128; k < ks * 128 + 128; ++k)
            acc += x1L[k] * w2[k * 512 + e * 64 + d];
        ps[ks][d] = acc;
        __syncthreads();
        if (t < 64)
            qhL[t] = b2[e * 64 + t] + ps[0][t] + ps[1][t] + ps[2][t] + ps[3][t];
        __syncthreads();
        const float* row = w_kv + (size_t)t * 1024 + e * 128;   // K-half of head e
        float a2 = 0.f;
#pragma unroll
        for (int dd = 0; dd < 64; dd += 4) {
            float4 wv4 = *(const float4*)(row + dd);
            a2 += qhL[dd] * wv4.x + qhL[dd + 1] * wv4.y + qhL[dd + 2] * wv4.z + qhL[dd + 3] * wv4.w;
        }
        qkw[(b * 8 + e) * 256 + t] = (f16)(a2 * rms_w[t]);
    } else {
        // ---- M role: (e, 8-c tile) ----
        int mb = blk - 64;
        int e = mb >> 5, c0 = (mb & 31) * 8;
        {
            int d = t & 63, cc = t >> 6;
            wv[d][cc]     = w_kv[(size_t)(c0 + cc) * 1024 + e * 128 + 64 + d];
            wv[d][cc + 4] = w_kv[(size_t)(c0 + cc + 4) * 1024 + e * 128 + 64 + d];
        }
        __syncthreads();
        int o = t;
        float acc[8];
#pragma unroll
        for (int c = 0; c < 8; ++c) acc[c] = 0.f;
#pragma unroll 4
        for (int d = 0; d < 64; ++d) {
            float wo = w_out[(size_t)(e * 64 + d) * 256 + o];
            float4 wa = *(const float4*)&wv[d][0];
            float4 wb = *(const float4*)&wv[d][4];
            acc[0] += wa.x * wo; acc[1] += wa.y * wo; acc[2] += wa.z * wo; acc[3] += wa.w * wo;
            acc[4] += wb.x * wo; acc[5] += wb.y * wo; acc[6] += wb.z * wo; acc[7] += wb.w * wo;
        }
        f16x8 ov;
#pragma unroll
        for (int c = 0; c < 8; ++c) ov[c] = (f16)(acc[c] * rms_w[c0 + c]);
        *(f16x8*)(mtp + ((size_t)((e * 256 + c0) >> 3) * 256 + o) * 8) = ov;
    }
}

// ---------------------------------------------------------------------------
// k_attn v5b: merged load+dots (R6 structure) with CORRECTED per-(px,n) rinv:
// each wave's wredS[w][m16] already holds the FULL 256-ch sumsq of block
// n=w&7 for px=(w>>3)*16+m16 -> rv[nn] = rsqrt(wredS[ph*8+nn][pl]/256+eps),
// no cross-n summation (R6's bug). 3 barriers total.
// ---------------------------------------------------------------------------
__launch_bounds__(1024, 4)
__global__ void k_attn(const float* __restrict__ cin, const f16* __restrict__ qkw,
                       const f16* __restrict__ mtp, const float* __restrict__ b_out,
                       float* __restrict__ out) {
    int blk = blockIdx.x;
    int b = blk & 7;
    int hw0 = (blk >> 3) * 32;
    int t = threadIdx.x;
    int lane = t & 63, w = t >> 6;        // w 0..15
    int m16 = lane & 15, quad = lane >> 4;
    int half = lane >> 5;                 // 0/1

    __shared__ char A[32 * 4096];         // 131072 B, swizzled f16 [32px][2048k]
    __shared__ float dotsP[8][8][32];     //   8192 B [n][e][px]
    __shared__ float wredS[16][16];       //   1024 B [w][m16]: full 256-ch sumsq
    __shared__ f16  attnH[8 * 32 * 8];    //   4096 B [e][px][n]

    // ---- phase 1: per-wave load (16px x 256ch) -> A + sumsq, then dots ----
    int n = w & 7, pxh = w >> 3;
    int px = pxh * 16 + m16;
    {
        const float* cb0 = cin + (((size_t)b * 2048) << 10) + hw0 + px;
        int chb = n * 256 + quad * 64;
        float ss = 0.f;
#pragma unroll
        for (int g = 0; g < 4; ++g) {
            float v[16];
#pragma unroll
            for (int j = 0; j < 16; ++j)
                v[j] = cb0[(size_t)(chb + g * 16 + j) << 10];
            f16x8 h0, h1;
#pragma unroll
            for (int j = 0; j < 8; ++j) { ss += v[j] * v[j]; h0[j] = (f16)v[j]; }
#pragma unroll
            for (int j = 0; j < 8; ++j) { float x = v[8 + j]; ss += x * x; h1[j] = (f16)x; }
            *(f16x8*)a_addr(A, px, chb + g * 16)     = h0;
            *(f16x8*)a_addr(A, px, chb + g * 16 + 8) = h1;
        }
        ss += __shfl_xor(ss, 16);         // combine quad 0<->1, 2<->3
        ss += __shfl_xor(ss, 32);         // combine quad pairs
        if (lane < 16) wredS[w][m16] = ss;   // sumsq over 256 ch of block n, px
    }
    {   // dots: reads only the A-chunk THIS wave just wrote (same-wave DS order)
        f32x4 d0 = {0.f, 0.f, 0.f, 0.f};
        const f16* qrow = qkw + (size_t)b * 2048 + (m16 & 7) * 256;
#pragma unroll
        for (int ks = 0; ks < 8; ++ks) {
            f16x8 a0 = *(const f16x8*)a_addr(A, px, n * 256 + ks * 32 + quad * 8);
            f16x8 bq = *(const f16x8*)(qrow + ks * 32 + quad * 8);
            d0 = __builtin_amdgcn_mfma_f32_16x16x32_f16(a0, bq, d0, 0, 0, 0);
        }
        if (m16 < 8) {   // D: col=m16=e, row=quad*4+r
#pragma unroll
            for (int r = 0; r < 4; ++r) dotsP[n][m16][pxh * 16 + quad * 4 + r] = d0[r];
        }
    }
    __syncthreads();

    // ---- phase 2: pb preload (in flight across attn) + attn-compute ----
    int o = w * 16 + m16;
    f16x8 pb[8];
#pragma unroll
    for (int ks = 0; ks < 8; ++ks)
        pb[ks] = *(const f16x8*)(mtp + ((size_t)(ks * 4 + quad) * 256 + o) * 8);

    if (t < 256) {        // one softmax per (px,e); rinv PER (px,n) — R6 fix
        int e = t >> 5, p = t & 31;
        int ph = p >> 4, pl = p & 15;
        float rv[8], l[8];
#pragma unroll
        for (int nn = 0; nn < 8; ++nn)
            rv[nn] = rsqrtf(wredS[ph * 8 + nn][pl] * (1.f / 256.f) + 1e-6f);
#pragma unroll
        for (int nn = 0; nn < 8; ++nn) l[nn] = dotsP[nn][e][p] * rv[nn] * 0.125f;
        float mx = l[0];
#pragma unroll
        for (int nn = 1; nn < 8; ++nn) mx = fmaxf(mx, l[nn]);
        float s = 0.f;
#pragma unroll
        for (int nn = 0; nn < 8; ++nn) { l[nn] = __expf(l[nn] - mx); s += l[nn]; }
        float inv = 1.f / s;
        f16x8 av;
#pragma unroll
        for (int nn = 0; nn < 8; ++nn) av[nn] = (f16)(l[nn] * inv * rv[nn]);
        *(f16x8*)(attnH + e * 256 + p * 8) = av;
    }
    __syncthreads();

    // ---- phase 3: cheap blend (in place over A) ----
    {
        int bpx = lane & 31;
        int c0 = (w + half * 16) * 8;     // halves 16 windows apart -> 2-way
        f16x8 cv[8];
#pragma unroll
        for (int nn = 0; nn < 8; ++nn)
            cv[nn] = *(const f16x8*)a_addr(A, bpx, nn * 256 + c0);
#pragma unroll
        for (int e = 0; e < 8; ++e) {
            f16x8 av = *(const f16x8*)(attnH + e * 256 + bpx * 8);
            f16x8 r = {};
#pragma unroll
            for (int nn = 0; nn < 8; ++nn) {
                f16 an = av[nn];
#pragma unroll
                for (int j = 0; j < 8; ++j) r[j] += cv[nn][j] * an;   // v_pk_fma_f16
            }
            *(f16x8*)a_addr(A, bpx, e * 256 + c0) = r;
        }
    }
    __syncthreads();

    // ---- phase 4: GEMM out[32p][256o] = A[32][2048] @ M (wave -> o-slice) ----
    {
        f32x4 acc0 = {0.f, 0.f, 0.f, 0.f};
        f32x4 acc1 = {0.f, 0.f, 0.f, 0.f};
#pragma unroll
        for (int ks = 0; ks < 8; ++ks) {   // preloaded B
            int k = ks * 32 + quad * 8;
            f16x8 af0 = *(const f16x8*)a_addr(A, m16, k);
            f16x8 af1 = *(const f16x8*)a_addr(A, m16 + 16, k);
            acc0 = __builtin_amdgcn_mfma_f32_16x16x32_f16(af0, pb[ks], acc0, 0, 0, 0);
            acc1 = __builtin_amdgcn_mfma_f32_16x16x32_f16(af1, pb[ks], acc1, 0, 0, 0);
        }
#pragma unroll 8
        for (int ks = 8; ks < 64; ++ks) {
            int k = (ks >> 3) * 256 + (ks & 7) * 32 + quad * 8;
            int kchunk = k >> 3;
            f16x8 bfr = *(const f16x8*)(mtp + ((size_t)kchunk * 256 + o) * 8);
            f16x8 af0 = *(const f16x8*)a_addr(A, m16, k);
            f16x8 af1 = *(const f16x8*)a_addr(A, m16 + 16, k);
            acc0 = __builtin_amdgcn_mfma_f32_16x16x32_f16(af0, bfr, acc0, 0, 0, 0);
            acc1 = __builtin_amdgcn_mfma_f32_16x16x32_f16(af1, bfr, acc1, 0, 0, 0);
        }
        float bo = b_out[o];
        float* drow = out + ((size_t)b * 256 + o) * 1024 + hw0;
        float4 v0 = {acc0[0] + bo, acc0[1] + bo, acc0[2] + bo, acc0[3] + bo};
        float4 v1 = {acc1[0] + bo, acc1[1] + bo, acc1[2] + bo, acc1[3] + bo};
        *(float4*)(drow + quad * 4)      = v0;   // px 0..15 half
        *(float4*)(drow + 16 + quad * 4) = v1;   // px 16..31 half
    }
}

extern "C" void kernel_launch(void* const* d_in, const int* in_sizes, int n_in,
                              void* d_out, int out_size, void* d_ws, size_t ws_size,
                              hipStream_t stream) {
    (void)in_sizes; (void)n_in; (void)out_size; (void)ws_size;
    const int*   q     = (const int*)d_in[0];
    const float* c     = (const float*)d_in[1];
    const float* rms_w = (const float*)d_in[2];
    const float* emb   = (const float*)d_in[3];
    const float* w1    = (const float*)d_in[4];
    const float* b1    = (const float*)d_in[5];
    const float* w2    = (const float*)d_in[6];
    const float* b2    = (const float*)d_in[7];
    const float* w_kv  = (const float*)d_in[8];
    const float* w_out = (const float*)d_in[9];
    const float* b_out = (const float*)d_in[10];
    float* out = (float*)d_out;

    // ws layout: qkw [8b][8e][256c] f16 = 32 KiB at 0; mtp [256kc][256o][8] f16 = 1 MiB
    char* ws = (char*)d_ws;
    f16* qkw = (f16*)ws;                 // [0, 32768)
    f16* mtp = (f16*)(ws + 32768);       // [32768, +1 MiB)

    k_setup<<<320, 256, 0, stream>>>(q, emb, w1, b1, w2, b2, w_kv, w_out, rms_w, qkw, mtp);
    k_attn <<<256, 1024, 0, stream>>>(c, qkw, mtp, b_out, out);
}